// Round 3
// baseline (83.237 us; speedup 1.0000x reference)
//
#include <hip/hip_runtime.h>
#include <hip/hip_bf16.h>
#include <math.h>

// Problem constants (fixed by setup_inputs)
#define B_DOC 32
#define S_MAX 40
#define T_K 64
#define N_DIM 512
#define B_SENT (B_DOC * S_MAX)      // 1280
#define MAXDOC (S_MAX * T_K)        // 2560
#define KCHUNK 4                    // fea GEMV k-split

__device__ __forceinline__ float fast_tanh(float x) {
    float e = __expf(2.0f * x);
    return 1.0f - 2.0f * __builtin_amdgcn_rcpf(e + 1.0f);
}

// ---------------- prep: fully parallel scans --------------------------------
__global__ __launch_bounds__(256) void prep_kernel(
        const int* __restrict__ seq_lens2, const int* __restrict__ sent_lens,
        int* __restrict__ doc_ids, int* __restrict__ sent_local,
        int* __restrict__ doc_word_off, int* __restrict__ sent_start_g,
        int* __restrict__ doc_words_total) {
    __shared__ int ss[B_DOC + 1];
    __shared__ int wc[B_SENT + 1];
    __shared__ int wsum[4];
    int tid = threadIdx.x;
    int lane = tid & 63, w = tid >> 6;

    int ls[5];
    #pragma unroll
    for (int k = 0; k < 5; ++k) ls[k] = seq_lens2[tid * 5 + k];
    int sum = ls[0] + ls[1] + ls[2] + ls[3] + ls[4];

    int scan = sum;
    #pragma unroll
    for (int off = 1; off < 64; off <<= 1) {
        int v = __shfl_up(scan, off, 64);
        if (lane >= off) scan += v;
    }
    if (lane == 63) wsum[w] = scan;

    if (w == 0) {
        int sl = (lane < B_DOC) ? sent_lens[lane] : 0;
        int sc2 = sl;
        #pragma unroll
        for (int off = 1; off < 64; off <<= 1) {
            int v = __shfl_up(sc2, off, 64);
            if (lane >= off) sc2 += v;
        }
        if (lane < B_DOC) ss[lane + 1] = sc2;
        if (lane == 0) ss[0] = 0;
    }
    __syncthreads();

    int wbase = 0;
    for (int i = 0; i < w; ++i) wbase += wsum[i];
    int excl = wbase + scan - sum;
    #pragma unroll
    for (int k = 0; k < 5; ++k) { wc[tid * 5 + k] = excl; excl += ls[k]; }
    if (tid == 255) wc[B_SENT] = excl;
    __syncthreads();

    if (tid <= B_DOC) sent_start_g[tid] = ss[tid];
    if (tid < B_DOC) doc_words_total[tid] = wc[ss[tid + 1]] - wc[ss[tid]];

    for (int i = tid; i < B_SENT; i += 256) {
        int lo = 0, hi = B_DOC - 1;
        while (lo < hi) { int mid = (lo + hi + 1) >> 1; if (ss[mid] <= i) lo = mid; else hi = mid - 1; }
        doc_ids[i] = lo;
        sent_local[i] = i - ss[lo];
        doc_word_off[i] = wc[i] - wc[ss[lo]];
    }
}

// ---------------- dec_fea partials: k-split GEMV ----------------------------
__global__ __launch_bounds__(256) void fea_kernel(
        const float* __restrict__ s_t_hat, const float* __restrict__ sent_s_t_hat,
        const float* __restrict__ Wd, const float* __restrict__ bd,
        const float* __restrict__ Wsd, const float* __restrict__ bsd,
        float* __restrict__ fea_part) {
    int blk = blockIdx.x;
    int c = blk & (KCHUNK - 1);
    int b = (blk >> 2) & 31;
    int m = blk >> 7;
    const int KC = N_DIM / KCHUNK;   // 128
    const float* x = (m ? sent_s_t_hat : s_t_hat) + b * N_DIM + c * KC;
    const float* W = (m ? Wsd : Wd) + (size_t)c * KC * N_DIM;
    const float* bias = (m ? bsd : bd);
    float* out = fea_part + ((size_t)(m * 32 + b) * KCHUNK + c) * N_DIM;
    __shared__ float xs[128];
    int tid = threadIdx.x;
    if (tid < KC) xs[tid] = x[tid];
    __syncthreads();
    float a0 = 0.f, a1 = 0.f;
    if (c == 0) { a0 = bias[tid]; a1 = bias[tid + 256]; }
    #pragma unroll 8
    for (int k = 0; k < KC; ++k) {
        float xv = xs[k];
        a0 = fmaf(xv, W[k * N_DIM + tid], a0);
        a1 = fmaf(xv, W[k * N_DIM + tid + 256], a1);
    }
    out[tid] = a0;
    out[tid + 256] = a1;
}

// ---------------- sentence-level attention ----------------------------------
__global__ __launch_bounds__(256) void sent_attn_kernel(
        const float* __restrict__ sef, const float* __restrict__ fea_part,
        const float* __restrict__ sv_w, const float* __restrict__ mask,
        float* __restrict__ out_sent) {
    int b = blockIdx.x;
    __shared__ float df[N_DIM];
    __shared__ float vw[N_DIM];
    __shared__ float sc[S_MAX];
    int tid = threadIdx.x;
    const float* fp = fea_part + (size_t)(32 + b) * KCHUNK * N_DIM;
    for (int i = tid; i < N_DIM; i += 256) {
        df[i] = fp[i] + fp[N_DIM + i] + fp[2 * N_DIM + i] + fp[3 * N_DIM + i];
        vw[i] = sv_w[i];
    }
    __syncthreads();
    int w = tid >> 6, lane = tid & 63;
    const float4* sef4 = (const float4*)(sef + (size_t)b * S_MAX * N_DIM);
    const float4* df4 = (const float4*)df;
    const float4* vw4 = (const float4*)vw;
    for (int t = w; t < S_MAX; t += 4) {
        float acc = 0.0f;
        #pragma unroll
        for (int j = 0; j < 2; ++j) {
            int n4 = lane + 64 * j;
            float4 e = sef4[t * 128 + n4];
            float4 d = df4[n4];
            float4 v = vw4[n4];
            acc = fmaf(v.x, fast_tanh(e.x + d.x), acc);
            acc = fmaf(v.y, fast_tanh(e.y + d.y), acc);
            acc = fmaf(v.z, fast_tanh(e.z + d.z), acc);
            acc = fmaf(v.w, fast_tanh(e.w + d.w), acc);
        }
        #pragma unroll
        for (int off = 32; off >= 1; off >>= 1) acc += __shfl_xor(acc, off, 64);
        if (lane == 0) sc[t] = acc;
    }
    __syncthreads();
    if (tid < 64) {
        bool valid = tid < S_MAX;
        float x = valid ? sc[tid] : -INFINITY;
        float m = x;
        #pragma unroll
        for (int off = 32; off >= 1; off >>= 1) m = fmaxf(m, __shfl_xor(m, off, 64));
        float mk = valid ? mask[b * S_MAX + tid] : 0.0f;
        float e = valid ? __expf(x - m) * mk : 0.0f;
        float ssum = e;
        #pragma unroll
        for (int off = 32; off >= 1; off >>= 1) ssum += __shfl_xor(ssum, off, 64);
        if (valid) out_sent[b * S_MAX + tid] = e / ssum;
    }
}

// ---------------- fused: word attention + mult + context partial ------------
// 512 threads (8 waves) per sentence; 4 resident blocks/CU -> 100% occupancy.
__global__ __launch_bounds__(512, 8) void fused_kernel(
        const float* __restrict__ ef, const float* __restrict__ eo,
        const float* __restrict__ fea_part, const float* __restrict__ v_w,
        const float* __restrict__ sent_attn, const int* __restrict__ seq_lens2,
        const int* __restrict__ doc_ids, const int* __restrict__ sent_local,
        const int* __restrict__ doc_word_off, const int* __restrict__ sent_start,
        const int* __restrict__ doc_words_total, const int* __restrict__ mdl,
        const float* __restrict__ cov_in,
        float* __restrict__ part, float* __restrict__ out_attn,
        float* __restrict__ out_cov) {
    int s = blockIdx.x;
    int tid = threadIdx.x;
    __shared__ float df[N_DIM];
    __shared__ float vw[N_DIM];
    __shared__ float sc[T_K];
    __shared__ float mult[T_K];
    __shared__ float4 red[512];

    int doc = doc_ids[s];
    int len = seq_lens2[s];
    int maxdoc = mdl[0];

    const float* fp = fea_part + (size_t)doc * KCHUNK * N_DIM;
    df[tid] = fp[tid] + fp[N_DIM + tid] + fp[2 * N_DIM + tid] + fp[3 * N_DIM + tid];
    vw[tid] = v_w[tid];
    // coverage passthrough (1280 blocks x 64 = full array)
    if (tid < T_K) out_cov[s * T_K + tid] = cov_in[s * T_K + tid];
    __syncthreads();

    // ---- phase A: scores (8 waves, t stride 8; valid words only) ----
    int w = tid >> 6, lane = tid & 63;
    const float4* ef4 = (const float4*)(ef + (size_t)s * T_K * N_DIM);
    const float4* df4 = (const float4*)df;
    const float4* vw4 = (const float4*)vw;
    for (int t = w; t < len; t += 8) {
        float acc = 0.0f;
        #pragma unroll
        for (int j = 0; j < 2; ++j) {
            int n4 = lane + 64 * j;
            float4 e = ef4[t * 128 + n4];
            float4 d = df4[n4];
            float4 v = vw4[n4];
            acc = fmaf(v.x, fast_tanh(e.x + d.x), acc);
            acc = fmaf(v.y, fast_tanh(e.y + d.y), acc);
            acc = fmaf(v.z, fast_tanh(e.z + d.z), acc);
            acc = fmaf(v.w, fast_tanh(e.w + d.w), acc);
        }
        #pragma unroll
        for (int off = 32; off >= 1; off >>= 1) acc += __shfl_xor(acc, off, 64);
        if (lane == 0) sc[t] = acc;
    }
    __syncthreads();

    // ---- softmax + mult + attn_dist_sw scatter (one wave) ----
    if (tid < T_K) {
        bool valid = tid < len;
        float x = valid ? sc[tid] : -INFINITY;
        float m = x;
        #pragma unroll
        for (int off = 32; off >= 1; off >>= 1) m = fmaxf(m, __shfl_xor(m, off, 64));
        float e = valid ? __expf(x - m) : 0.0f;
        float ssum = e;
        #pragma unroll
        for (int off = 32; off >= 1; off >>= 1) ssum += __shfl_xor(ssum, off, 64);
        float sa = sent_attn[doc * S_MAX + sent_local[s]];
        float mu = valid ? sa * (e / ssum) : 0.0f;
        mult[tid] = mu;
        if (valid) out_attn[(size_t)doc * maxdoc + doc_word_off[s] + tid] = mu;
    }
    // tail zeroing: last sentence of each doc zeroes [doc_words, maxdoc)
    if (s + 1 == sent_start[doc + 1]) {
        int dwt = doc_words_total[doc];
        for (int i = dwt + tid; i < maxdoc; i += 512)
            out_attn[(size_t)doc * maxdoc + i] = 0.0f;
    }
    __syncthreads();

    // ---- phase B: weighted context partial (4-way word split) ----
    int nq = tid & 127;   // float4 column (512 floats)
    int tq = tid >> 7;    // 0..3 word-dim split
    float4 acc = {0.f, 0.f, 0.f, 0.f};
    const float4* e4 = (const float4*)(eo + (size_t)s * T_K * N_DIM);
    for (int t = tq; t < len; t += 4) {
        float m = mult[t];
        float4 e = e4[t * 128 + nq];
        acc.x = fmaf(m, e.x, acc.x);
        acc.y = fmaf(m, e.y, acc.y);
        acc.z = fmaf(m, e.z, acc.z);
        acc.w = fmaf(m, e.w, acc.w);
    }
    red[tid] = acc;
    __syncthreads();
    if (tid < 128) {
        float4 a = red[nq];
        float4 b1 = red[nq + 128];
        float4 c1 = red[nq + 256];
        float4 d1 = red[nq + 384];
        float4 r = {a.x + b1.x + c1.x + d1.x, a.y + b1.y + c1.y + d1.y,
                    a.z + b1.z + c1.z + d1.z, a.w + b1.w + c1.w + d1.w};
        ((float4*)(part + (size_t)s * N_DIM))[nq] = r;
    }
}

// ---------------- deterministic per-doc reduction: c_t ----------------------
__global__ __launch_bounds__(128) void reduce_kernel(
        const float* __restrict__ part, const int* __restrict__ sent_start,
        float* __restrict__ c_t) {
    int b = blockIdx.x;
    int nq = threadIdx.x;    // 128 float4 columns
    int st = sent_start[b], en = sent_start[b + 1];
    float4 acc = {0.f, 0.f, 0.f, 0.f};
    for (int s = st; s < en; ++s) {
        float4 p = ((const float4*)(part + (size_t)s * N_DIM))[nq];
        acc.x += p.x; acc.y += p.y; acc.z += p.z; acc.w += p.w;
    }
    ((float4*)(c_t + (size_t)b * N_DIM))[nq] = acc;
}

extern "C" void kernel_launch(void* const* d_in, const int* in_sizes, int n_in,
                              void* d_out, int out_size, void* d_ws, size_t ws_size,
                              hipStream_t stream) {
    const float* s_t_hat        = (const float*)d_in[0];
    const float* encoder_out    = (const float*)d_in[1];
    const float* encoder_feat   = (const float*)d_in[2];
    const int*   seq_lens2      = (const int*)d_in[3];
    const float* sent_s_t_hat   = (const float*)d_in[4];
    // d_in[5] sent_enc_outputs — unused by the reference computation
    const float* sent_enc_feat  = (const float*)d_in[6];
    const float* sent_pad_mask  = (const float*)d_in[7];
    const int*   sent_lens      = (const int*)d_in[8];
    const int*   max_doc_len    = (const int*)d_in[9];
    const float* coverage       = (const float*)d_in[10];
    const float* Wd             = (const float*)d_in[11];
    const float* bd             = (const float*)d_in[12];
    const float* v_w            = (const float*)d_in[13];
    const float* Wsd            = (const float*)d_in[14];
    const float* bsd            = (const float*)d_in[15];
    const float* sv_w           = (const float*)d_in[16];

    // output layout: c_t | attn_dist_sw | coverage | sent_attn
    float* out      = (float*)d_out;
    float* o_ct     = out;
    float* o_attn   = out + B_DOC * N_DIM;
    float* o_cov    = o_attn + B_DOC * MAXDOC;
    float* o_sent   = o_cov + B_SENT * T_K;

    // workspace layout (floats)
    float* ws          = (float*)d_ws;
    float* fea_part    = ws;                                   // 131072
    float* part        = ws + 131072;                          // 655360
    int*   ints        = (int*)(ws + 131072 + 655360);
    int*   doc_ids     = ints;
    int*   sent_local  = ints + B_SENT;
    int*   doc_w_off   = ints + 2 * B_SENT;
    int*   sent_start  = ints + 3 * B_SENT;
    int*   doc_wtot    = ints + 3 * B_SENT + 33;

    prep_kernel<<<1, 256, 0, stream>>>(seq_lens2, sent_lens, doc_ids, sent_local,
                                       doc_w_off, sent_start, doc_wtot);
    fea_kernel<<<2 * 32 * KCHUNK, 256, 0, stream>>>(s_t_hat, sent_s_t_hat, Wd, bd,
                                                    Wsd, bsd, fea_part);
    sent_attn_kernel<<<B_DOC, 256, 0, stream>>>(sent_enc_feat, fea_part, sv_w,
                                                sent_pad_mask, o_sent);
    fused_kernel<<<B_SENT, 512, 0, stream>>>(encoder_feat, encoder_out, fea_part,
                                             v_w, o_sent, seq_lens2, doc_ids,
                                             sent_local, doc_w_off, sent_start,
                                             doc_wtot, max_doc_len, coverage,
                                             part, o_attn, o_cov);
    reduce_kernel<<<B_DOC, 128, 0, stream>>>(part, sent_start, o_ct);
}

// Round 4
// 77.467 us; speedup vs baseline: 1.0745x; 1.0745x over previous
//
#include <hip/hip_runtime.h>
#include <hip/hip_bf16.h>
#include <math.h>

// Problem constants (fixed by setup_inputs)
#define B_DOC 32
#define S_MAX 40
#define T_K 64
#define N_DIM 512
#define B_SENT (B_DOC * S_MAX)      // 1280
#define MAXDOC (S_MAX * T_K)        // 2560
#define KCHUNK 4                    // fea GEMV k-split

__device__ __forceinline__ float fast_tanh(float x) {
    float e = __expf(2.0f * x);
    return 1.0f - 2.0f * __builtin_amdgcn_rcpf(e + 1.0f);
}

// ---------------- merged: prep (block 256) + fea GEMV (blocks 0..255) -------
__global__ __launch_bounds__(256) void prep_fea_kernel(
        const int* __restrict__ seq_lens2, const int* __restrict__ sent_lens,
        const float* __restrict__ s_t_hat, const float* __restrict__ sent_s_t_hat,
        const float* __restrict__ Wd, const float* __restrict__ bd,
        const float* __restrict__ Wsd, const float* __restrict__ bsd,
        float* __restrict__ fea_part,
        int* __restrict__ doc_ids, int* __restrict__ sent_local,
        int* __restrict__ doc_word_off, int* __restrict__ sent_start_g,
        int* __restrict__ doc_words_total) {
    int tid = threadIdx.x;
    if (blockIdx.x == 256) {
        // ---- prep: fully parallel scans ----
        __shared__ int ss[B_DOC + 1];
        __shared__ int wc[B_SENT + 1];
        __shared__ int wsum[4];
        int lane = tid & 63, w = tid >> 6;

        int ls[5];
        #pragma unroll
        for (int k = 0; k < 5; ++k) ls[k] = seq_lens2[tid * 5 + k];
        int sum = ls[0] + ls[1] + ls[2] + ls[3] + ls[4];

        int scan = sum;
        #pragma unroll
        for (int off = 1; off < 64; off <<= 1) {
            int v = __shfl_up(scan, off, 64);
            if (lane >= off) scan += v;
        }
        if (lane == 63) wsum[w] = scan;

        if (w == 0) {
            int sl = (lane < B_DOC) ? sent_lens[lane] : 0;
            int sc2 = sl;
            #pragma unroll
            for (int off = 1; off < 64; off <<= 1) {
                int v = __shfl_up(sc2, off, 64);
                if (lane >= off) sc2 += v;
            }
            if (lane < B_DOC) ss[lane + 1] = sc2;
            if (lane == 0) ss[0] = 0;
        }
        __syncthreads();

        int wbase = 0;
        for (int i = 0; i < w; ++i) wbase += wsum[i];
        int excl = wbase + scan - sum;
        #pragma unroll
        for (int k = 0; k < 5; ++k) { wc[tid * 5 + k] = excl; excl += ls[k]; }
        if (tid == 255) wc[B_SENT] = excl;
        __syncthreads();

        if (tid <= B_DOC) sent_start_g[tid] = ss[tid];
        if (tid < B_DOC) doc_words_total[tid] = wc[ss[tid + 1]] - wc[ss[tid]];

        for (int i = tid; i < B_SENT; i += 256) {
            int lo = 0, hi = B_DOC - 1;
            while (lo < hi) { int mid = (lo + hi + 1) >> 1; if (ss[mid] <= i) lo = mid; else hi = mid - 1; }
            doc_ids[i] = lo;
            sent_local[i] = i - ss[lo];
            doc_word_off[i] = wc[i] - wc[ss[lo]];
        }
    } else {
        // ---- fea: k-split GEMV partials ----
        int blk = blockIdx.x;
        int c = blk & (KCHUNK - 1);
        int b = (blk >> 2) & 31;
        int m = blk >> 7;
        const int KC = N_DIM / KCHUNK;   // 128
        const float* x = (m ? sent_s_t_hat : s_t_hat) + b * N_DIM + c * KC;
        const float* W = (m ? Wsd : Wd) + (size_t)c * KC * N_DIM;
        const float* bias = (m ? bsd : bd);
        float* out = fea_part + ((size_t)(m * 32 + b) * KCHUNK + c) * N_DIM;
        __shared__ float xs[128];
        if (tid < KC) xs[tid] = x[tid];
        __syncthreads();
        float a0 = 0.f, a1 = 0.f;
        if (c == 0) { a0 = bias[tid]; a1 = bias[tid + 256]; }
        #pragma unroll 8
        for (int k = 0; k < KC; ++k) {
            float xv = xs[k];
            a0 = fmaf(xv, W[k * N_DIM + tid], a0);
            a1 = fmaf(xv, W[k * N_DIM + tid + 256], a1);
        }
        out[tid] = a0;
        out[tid + 256] = a1;
    }
}

// ---------------- sentence-level attention ----------------------------------
__global__ __launch_bounds__(256) void sent_attn_kernel(
        const float* __restrict__ sef, const float* __restrict__ fea_part,
        const float* __restrict__ sv_w, const float* __restrict__ mask,
        float* __restrict__ out_sent) {
    int b = blockIdx.x;
    __shared__ float df[N_DIM];
    __shared__ float vw[N_DIM];
    __shared__ float sc[S_MAX];
    int tid = threadIdx.x;
    const float* fp = fea_part + (size_t)(32 + b) * KCHUNK * N_DIM;
    for (int i = tid; i < N_DIM; i += 256) {
        df[i] = fp[i] + fp[N_DIM + i] + fp[2 * N_DIM + i] + fp[3 * N_DIM + i];
        vw[i] = sv_w[i];
    }
    __syncthreads();
    int w = tid >> 6, lane = tid & 63;
    const float4* sef4 = (const float4*)(sef + (size_t)b * S_MAX * N_DIM);
    const float4* df4 = (const float4*)df;
    const float4* vw4 = (const float4*)vw;
    for (int t = w; t < S_MAX; t += 4) {
        float acc = 0.0f;
        #pragma unroll
        for (int j = 0; j < 2; ++j) {
            int n4 = lane + 64 * j;
            float4 e = sef4[t * 128 + n4];
            float4 d = df4[n4];
            float4 v = vw4[n4];
            acc = fmaf(v.x, fast_tanh(e.x + d.x), acc);
            acc = fmaf(v.y, fast_tanh(e.y + d.y), acc);
            acc = fmaf(v.z, fast_tanh(e.z + d.z), acc);
            acc = fmaf(v.w, fast_tanh(e.w + d.w), acc);
        }
        #pragma unroll
        for (int off = 32; off >= 1; off >>= 1) acc += __shfl_xor(acc, off, 64);
        if (lane == 0) sc[t] = acc;
    }
    __syncthreads();
    if (tid < 64) {
        bool valid = tid < S_MAX;
        float x = valid ? sc[tid] : -INFINITY;
        float m = x;
        #pragma unroll
        for (int off = 32; off >= 1; off >>= 1) m = fmaxf(m, __shfl_xor(m, off, 64));
        float mk = valid ? mask[b * S_MAX + tid] : 0.0f;
        float e = valid ? __expf(x - m) * mk : 0.0f;
        float ssum = e;
        #pragma unroll
        for (int off = 32; off >= 1; off >>= 1) ssum += __shfl_xor(ssum, off, 64);
        if (valid) out_sent[b * S_MAX + tid] = e / ssum;
    }
}

// ---------------- fused online: scores + softmax + context in ONE pass ------
// 256 threads = 4 waves; wave w processes words t = w, w+4, ... maintaining
// running (m, l, O) flash-style. Both streams (ef for scores, eo for context)
// are read in the same iteration -> 4KB in flight per wave + 1-ahead ef
// prefetch. Single cross-wave combine at the end.
__global__ __launch_bounds__(256, 4) void fused_kernel(
        const float* __restrict__ ef, const float* __restrict__ eo,
        const float* __restrict__ fea_part, const float* __restrict__ v_w,
        const float* __restrict__ sent_attn, const int* __restrict__ seq_lens2,
        const int* __restrict__ doc_ids, const int* __restrict__ sent_local,
        const int* __restrict__ doc_word_off, const int* __restrict__ sent_start,
        const int* __restrict__ doc_words_total, const int* __restrict__ mdl,
        const float* __restrict__ cov_in,
        float* __restrict__ part, float* __restrict__ out_attn,
        float* __restrict__ out_cov) {
    int s = blockIdx.x;
    int tid = threadIdx.x;
    int w = tid >> 6, lane = tid & 63;
    __shared__ float sc[T_K];
    __shared__ float wm[4], wl[4];
    __shared__ float4 red[4][128];

    int doc = doc_ids[s];
    int len = seq_lens2[s];
    int maxdoc = mdl[0];

    // dec_fea (sum of 4 k-chunks) and v_w into registers:
    // lane owns float4 columns {lane, lane+64} (dims 4*lane.. and 256+4*lane..)
    const float4* fp4 = (const float4*)(fea_part + (size_t)doc * KCHUNK * N_DIM);
    float4 d0 = fp4[lane], d1 = fp4[64 + lane];
    #pragma unroll
    for (int c = 1; c < KCHUNK; ++c) {
        float4 a = fp4[c * 128 + lane], b = fp4[c * 128 + 64 + lane];
        d0.x += a.x; d0.y += a.y; d0.z += a.z; d0.w += a.w;
        d1.x += b.x; d1.y += b.y; d1.z += b.z; d1.w += b.w;
    }
    const float4* vw4 = (const float4*)v_w;
    float4 v0 = vw4[lane], v1 = vw4[64 + lane];

    // coverage passthrough
    if (tid < T_K) out_cov[s * T_K + tid] = cov_in[s * T_K + tid];

    const float4* ef4 = (const float4*)(ef + (size_t)s * T_K * N_DIM);
    const float4* eo4 = (const float4*)(eo + (size_t)s * T_K * N_DIM);

    float m_w = -INFINITY, l_w = 0.0f;
    float4 O0 = {0.f, 0.f, 0.f, 0.f}, O1 = {0.f, 0.f, 0.f, 0.f};

    float4 ea0, ea1;
    if (w < len) { ea0 = ef4[w * 128 + lane]; ea1 = ef4[w * 128 + 64 + lane]; }
    for (int t = w; t < len; t += 4) {
        // context stream for current word (consumed at end of iter)
        float4 p0 = eo4[t * 128 + lane];
        float4 p1 = eo4[t * 128 + 64 + lane];
        // 1-ahead prefetch of score stream
        float4 eb0, eb1;
        int tn = t + 4;
        if (tn < len) { eb0 = ef4[tn * 128 + lane]; eb1 = ef4[tn * 128 + 64 + lane]; }
        // score = v . tanh(ef + df)
        float acc;
        acc  = v0.x * fast_tanh(ea0.x + d0.x);
        acc = fmaf(v0.y, fast_tanh(ea0.y + d0.y), acc);
        acc = fmaf(v0.z, fast_tanh(ea0.z + d0.z), acc);
        acc = fmaf(v0.w, fast_tanh(ea0.w + d0.w), acc);
        acc = fmaf(v1.x, fast_tanh(ea1.x + d1.x), acc);
        acc = fmaf(v1.y, fast_tanh(ea1.y + d1.y), acc);
        acc = fmaf(v1.z, fast_tanh(ea1.z + d1.z), acc);
        acc = fmaf(v1.w, fast_tanh(ea1.w + d1.w), acc);
        #pragma unroll
        for (int off = 32; off >= 1; off >>= 1) acc += __shfl_xor(acc, off, 64);
        if (lane == 0) sc[t] = acc;
        // online softmax update (acc is wave-uniform after full butterfly)
        if (acc > m_w) {
            float r = __expf(m_w - acc);
            l_w *= r;
            O0.x *= r; O0.y *= r; O0.z *= r; O0.w *= r;
            O1.x *= r; O1.y *= r; O1.z *= r; O1.w *= r;
            m_w = acc;
        }
        float p = __expf(acc - m_w);
        l_w += p;
        O0.x = fmaf(p, p0.x, O0.x); O0.y = fmaf(p, p0.y, O0.y);
        O0.z = fmaf(p, p0.z, O0.z); O0.w = fmaf(p, p0.w, O0.w);
        O1.x = fmaf(p, p1.x, O1.x); O1.y = fmaf(p, p1.y, O1.y);
        O1.z = fmaf(p, p1.z, O1.z); O1.w = fmaf(p, p1.w, O1.w);
        ea0 = eb0; ea1 = eb1;
    }

    // ---- cross-wave combine ----
    if (lane == 0) { wm[w] = m_w; wl[w] = l_w; }
    __syncthreads();
    float m = fmaxf(fmaxf(wm[0], wm[1]), fmaxf(wm[2], wm[3]));
    float l = __expf(wm[0] - m) * wl[0] + __expf(wm[1] - m) * wl[1]
            + __expf(wm[2] - m) * wl[2] + __expf(wm[3] - m) * wl[3];
    float fw = __expf(m_w - m);
    red[w][lane].x = O0.x * fw; red[w][lane].y = O0.y * fw;
    red[w][lane].z = O0.z * fw; red[w][lane].w = O0.w * fw;
    red[w][64 + lane].x = O1.x * fw; red[w][64 + lane].y = O1.y * fw;
    red[w][64 + lane].z = O1.z * fw; red[w][64 + lane].w = O1.w * fw;
    float sa = sent_attn[doc * S_MAX + sent_local[s]];
    float inv = sa / l;
    __syncthreads();
    if (tid < 128) {
        float4 a = red[0][tid], b = red[1][tid], c = red[2][tid], d = red[3][tid];
        float4 r = {(a.x + b.x + c.x + d.x) * inv, (a.y + b.y + c.y + d.y) * inv,
                    (a.z + b.z + c.z + d.z) * inv, (a.w + b.w + c.w + d.w) * inv};
        ((float4*)(part + (size_t)s * N_DIM))[tid] = r;
    }
    // mult_attn scatter into attn_dist_sw
    if (tid < T_K && tid < len) {
        float mu = sa * __expf(sc[tid] - m) / l;
        out_attn[(size_t)doc * maxdoc + doc_word_off[s] + tid] = mu;
    }
    // tail zeroing: last sentence of each doc zeroes [doc_words, maxdoc)
    if (s + 1 == sent_start[doc + 1]) {
        int dwt = doc_words_total[doc];
        for (int i = dwt + tid; i < maxdoc; i += 256)
            out_attn[(size_t)doc * maxdoc + i] = 0.0f;
    }
}

// ---------------- deterministic per-doc reduction: c_t ----------------------
__global__ __launch_bounds__(128) void reduce_kernel(
        const float* __restrict__ part, const int* __restrict__ sent_start,
        float* __restrict__ c_t) {
    int b = blockIdx.x;
    int nq = threadIdx.x;    // 128 float4 columns
    int st = sent_start[b], en = sent_start[b + 1];
    float4 acc = {0.f, 0.f, 0.f, 0.f};
    for (int s = st; s < en; ++s) {
        float4 p = ((const float4*)(part + (size_t)s * N_DIM))[nq];
        acc.x += p.x; acc.y += p.y; acc.z += p.z; acc.w += p.w;
    }
    ((float4*)(c_t + (size_t)b * N_DIM))[nq] = acc;
}

extern "C" void kernel_launch(void* const* d_in, const int* in_sizes, int n_in,
                              void* d_out, int out_size, void* d_ws, size_t ws_size,
                              hipStream_t stream) {
    const float* s_t_hat        = (const float*)d_in[0];
    const float* encoder_out    = (const float*)d_in[1];
    const float* encoder_feat   = (const float*)d_in[2];
    const int*   seq_lens2      = (const int*)d_in[3];
    const float* sent_s_t_hat   = (const float*)d_in[4];
    // d_in[5] sent_enc_outputs — unused by the reference computation
    const float* sent_enc_feat  = (const float*)d_in[6];
    const float* sent_pad_mask  = (const float*)d_in[7];
    const int*   sent_lens      = (const int*)d_in[8];
    const int*   max_doc_len    = (const int*)d_in[9];
    const float* coverage       = (const float*)d_in[10];
    const float* Wd             = (const float*)d_in[11];
    const float* bd             = (const float*)d_in[12];
    const float* v_w            = (const float*)d_in[13];
    const float* Wsd            = (const float*)d_in[14];
    const float* bsd            = (const float*)d_in[15];
    const float* sv_w           = (const float*)d_in[16];

    // output layout: c_t | attn_dist_sw | coverage | sent_attn
    float* out      = (float*)d_out;
    float* o_ct     = out;
    float* o_attn   = out + B_DOC * N_DIM;
    float* o_cov    = o_attn + B_DOC * MAXDOC;
    float* o_sent   = o_cov + B_SENT * T_K;

    // workspace layout (floats)
    float* ws          = (float*)d_ws;
    float* fea_part    = ws;                                   // 131072
    float* part        = ws + 131072;                          // 655360
    int*   ints        = (int*)(ws + 131072 + 655360);
    int*   doc_ids     = ints;
    int*   sent_local  = ints + B_SENT;
    int*   doc_w_off   = ints + 2 * B_SENT;
    int*   sent_start  = ints + 3 * B_SENT;
    int*   doc_wtot    = ints + 3 * B_SENT + 33;

    prep_fea_kernel<<<257, 256, 0, stream>>>(seq_lens2, sent_lens, s_t_hat,
                                             sent_s_t_hat, Wd, bd, Wsd, bsd,
                                             fea_part, doc_ids, sent_local,
                                             doc_w_off, sent_start, doc_wtot);
    sent_attn_kernel<<<B_DOC, 256, 0, stream>>>(sent_enc_feat, fea_part, sv_w,
                                                sent_pad_mask, o_sent);
    fused_kernel<<<B_SENT, 256, 0, stream>>>(encoder_feat, encoder_out, fea_part,
                                             v_w, o_sent, seq_lens2, doc_ids,
                                             sent_local, doc_w_off, sent_start,
                                             doc_wtot, max_doc_len, coverage,
                                             part, o_attn, o_cov);
    reduce_kernel<<<B_DOC, 128, 0, stream>>>(part, sent_start, o_ct);
}